// Round 18
// baseline (69.989 us; speedup 1.0000x reference)
//
#include <hip/hip_runtime.h>
#include <hip/hip_bf16.h>
#include <math.h>

#define BB 2
#define CC 256
#define NH 8
#define HD 32
#define NN 2048
#define QBLK 64
// (1/sqrt(32)) * log2(e): softmax runs in the log2 domain
#define QK_SCALE 0.25500917f

typedef __attribute__((ext_vector_type(8))) short short8;
typedef __attribute__((ext_vector_type(8))) unsigned short ushort8;
typedef __attribute__((ext_vector_type(4))) float f32x4;

__device__ inline unsigned short f2bf(float f) {
    __hip_bfloat16 h = __float2bfloat16(f);
    return __builtin_bit_cast(unsigned short, h);
}
// bijective XCD-chunk swizzle (m204)
__device__ inline int xcd_chunk(int orig, int nwg) {
    int q = nwg >> 3, r = nwg & 7, x = orig & 7, s = orig >> 3;
    return (x < r ? x * (q + 1) : r * (q + 1) + (x - r) * q) + s;
}

// ---------------------------------------------------------------------------
// Stage 1: MFMA GEMM qkv = w_qkv @ x + b (R11 verbatim).
// ---------------------------------------------------------------------------
__global__ __launch_bounds__(256) void qkv_mfma(const float* __restrict__ x,
                                                const float* __restrict__ wq,
                                                const float* __restrict__ bias,
                                                unsigned short* __restrict__ qt,
                                                unsigned short* __restrict__ ktt,
                                                unsigned short* __restrict__ vt) {
    const int l = xcd_chunk(blockIdx.x, 768);
    const int m0 = (l % 12) * 64;
    const int xtile = l / 12;
    const int n0 = (xtile & 31) * 64;
    const int b = xtile >> 5;
    const int t = threadIdx.x, lane = t & 63, wid = t >> 6;
    const int g = lane >> 4, ln = lane & 15;
    __shared__ __align__(16) unsigned short Aw[4][64][36];
    __shared__ __align__(16) unsigned short Bx[4][64][36];
    f32x4 acc[4] = {};
    const int sm = t & 63, sch = t >> 6;
    const int pc = t >> 4, pn = t & 15;
    const int c0 = pc * 8, nl = pn * 4;
    const float* xb = x + (size_t)b * CC * NN + n0;
    for (int kh = 0; kh < 2; ++kh) {
        __syncthreads();
        {   // A: w_qkv fp32 -> bf16
            const float* wsrc = wq + (size_t)(m0 + sm) * CC + kh * 128 + sch * 32;
            float wv[32];
#pragma unroll
            for (int j = 0; j < 8; ++j) *(float4*)&wv[j * 4] = *(const float4*)&wsrc[j * 4];
#pragma unroll
            for (int j2 = 0; j2 < 4; ++j2) {
                ushort8 p;
#pragma unroll
                for (int e = 0; e < 8; ++e) p[e] = f2bf(wv[j2 * 8 + e]);
                *(ushort8*)&Aw[sch][sm][j2 * 8] = p;
            }
        }
        {   // B: x fp32 [c][n] -> bf16 [n][c] (register-patch transpose)
            const float* xsrc = xb + (size_t)(kh * 128 + c0) * NN + nl;
            float xv[8][4];
#pragma unroll
            for (int i = 0; i < 8; ++i) *(float4*)&xv[i][0] = *(const float4*)&xsrc[(size_t)i * NN];
#pragma unroll
            for (int i2 = 0; i2 < 4; ++i2) {
                ushort8 p;
#pragma unroll
                for (int e = 0; e < 8; ++e) p[e] = f2bf(xv[e][i2]);
                *(ushort8*)&Bx[pc >> 2][nl + i2][(pc & 3) * 8] = p;
            }
        }
        __syncthreads();
#pragma unroll
        for (int ks = 0; ks < 4; ++ks) {
            short8 aW = *(const short8*)&Aw[ks][wid * 16 + ln][g * 8];
#pragma unroll
            for (int nt = 0; nt < 4; ++nt) {
                short8 bX = *(const short8*)&Bx[ks][nt * 16 + ln][g * 8];
                acc[nt] = __builtin_amdgcn_mfma_f32_16x16x32_bf16(aW, bX, acc[nt], 0, 0, 0);
            }
        }
    }
    __syncthreads();
    unsigned short (*Tqk)[64][40] = (unsigned short (*)[64][40])&Aw[0][0][0];
    unsigned short (*Tv)[32][72]  = (unsigned short (*)[32][72])&Bx[0][0][0];
    {
        const int grp = wid >> 1;
        const int cl0 = (wid & 1) * 16 + 4 * g;
        const int gm0 = m0 + grp * 32;
        const int gtype = (gm0 % 96) >> 5;
        const float sc = (gtype == 0) ? QK_SCALE : 1.0f;
        float bv[4];
#pragma unroll
        for (int r = 0; r < 4; ++r) bv[r] = bias[gm0 + cl0 + r];
        if (gtype == 2) {
#pragma unroll
            for (int nt = 0; nt < 4; ++nt)
#pragma unroll
                for (int r = 0; r < 4; ++r)
                    Tv[grp][cl0 + r][nt * 16 + ln] = f2bf(acc[nt][r] + bv[r]);
        } else {
#pragma unroll
            for (int nt = 0; nt < 4; ++nt)
#pragma unroll
                for (int r = 0; r < 4; ++r)
                    Tqk[grp][nt * 16 + ln][cl0 + r] = f2bf((acc[nt][r] + bv[r]) * sc);
        }
    }
    __syncthreads();
#pragma unroll
    for (int grp2 = 0; grp2 < 2; ++grp2) {
        const int gm = m0 + grp2 * 32;
        const int gtype = (gm % 96) >> 5;
        const int head = gm / 96;
        if (gtype == 2) {
            const int cl = t >> 3, n8 = (t & 7) * 8;
            ushort8 v = *(const ushort8*)&Tv[grp2][cl][n8];
            *(ushort8*)&vt[((size_t)(b * NH + head) * HD + cl) * NN + n0 + n8] = v;
        } else {
            unsigned short* dst = (gtype == 0) ? qt : ktt;
            const int nr = t >> 2, c8 = (t & 3) * 8;
            ushort8 v = *(const ushort8*)&Tqk[grp2][nr][c8];
            *(ushort8*)&dst[((size_t)(b * NH + head) * NN + n0 + nr) * HD + c8] = v;
        }
    }
}

// ---------------------------------------------------------------------------
// Stage 2: barrier-free MFMA flash attention. R11 geometry (QBLK=64, 512
// blocks, minimal K/V traffic) + R17 per-qt4 narrow loop (live set ~85-90)
// + launch_bounds(512,6): VGPR cap ~84 -> 3 blocks/CU, 24 waves/CU.
// The cap squeezes ~5 regs (rematerializable addresses) — NOT R15's cap-32
// disaster (need-cap=58 -> 67MB scratch).
// ---------------------------------------------------------------------------
__global__ __launch_bounds__(512, 6) void attn_mfma(const unsigned short* __restrict__ Qt,
                                                    const unsigned short* __restrict__ Kt,
                                                    const unsigned short* __restrict__ Vt,
                                                    unsigned short* __restrict__ aout_t) {
    const int l = xcd_chunk(blockIdx.x, 512);
    const int n0 = (l & 31) * QBLK;
    const int bh = l >> 5;
    const int h = bh & 7, b = bh >> 3;
    const int t = threadIdx.x;
    const int lane = t & 63, w = t >> 6;
    const int g = lane >> 4, ln = lane & 15;
    __shared__ float Of[8][64][18];
    __shared__ float Ls[8][64];
    const unsigned short* qb = Qt + ((size_t)(b * NH + h) * NN + n0) * HD;
    const unsigned short* kb = Kt + (size_t)(b * NH + h) * NN * HD;
    const unsigned short* vb = Vt + (size_t)(b * NH + h) * HD * NN;
    short8 bQ[4];
#pragma unroll
    for (int qt4 = 0; qt4 < 4; ++qt4)
        bQ[qt4] = *(const short8*)&qb[(size_t)(qt4 * 16 + ln) * HD + g * 8];
    const int krow = 8 * (ln >> 2) + (ln & 3);
    const int wkey0 = w * 256;
    f32x4 oacc[4][2];
    const f32x4 zero4 = {0.f, 0.f, 0.f, 0.f};
#pragma unroll
    for (int qt4 = 0; qt4 < 4; ++qt4) { oacc[qt4][0] = zero4; oacc[qt4][1] = zero4; }
    float l_run[4] = {0.f, 0.f, 0.f, 0.f};
    short8 kA0 = *(const short8*)&kb[(size_t)(wkey0 + krow + 0) * HD + g * 8];
    short8 kA1 = *(const short8*)&kb[(size_t)(wkey0 + krow + 4) * HD + g * 8];
    for (int it = 0; it < 8; ++it) {
        const int kt0 = wkey0 + it * 32;
        short8 bV0 = *(const short8*)&vb[(size_t)ln * NN + kt0 + g * 8];
        short8 bV1 = *(const short8*)&vb[(size_t)(16 + ln) * NN + kt0 + g * 8];
        // per-qt4 processing: only one s0/s1/aP live at a time
#pragma unroll
        for (int qt4 = 0; qt4 < 4; ++qt4) {
            f32x4 s0, s1;
            __builtin_amdgcn_s_setprio(1);
            s0 = __builtin_amdgcn_mfma_f32_16x16x32_bf16(kA0, bQ[qt4], zero4, 0, 0, 0);
            s1 = __builtin_amdgcn_mfma_f32_16x16x32_bf16(kA1, bQ[qt4], zero4, 0, 0, 0);
            __builtin_amdgcn_s_setprio(0);
            short8 aP;
#pragma unroll
            for (int r = 0; r < 4; ++r) {
                float p0 = exp2f(s0[r]);
                float p1 = exp2f(s1[r]);
                s0[r] = p0; s1[r] = p1;
                aP[r] = (short)f2bf(p0);
                aP[4 + r] = (short)f2bf(p1);
            }
            l_run[qt4] += ((s0[0] + s0[1]) + (s0[2] + s0[3]))
                        + ((s1[0] + s1[1]) + (s1[2] + s1[3]));
            __builtin_amdgcn_s_setprio(1);
            oacc[qt4][0] = __builtin_amdgcn_mfma_f32_16x16x32_bf16(aP, bV0, oacc[qt4][0], 0, 0, 0);
            oacc[qt4][1] = __builtin_amdgcn_mfma_f32_16x16x32_bf16(aP, bV1, oacc[qt4][1], 0, 0, 0);
            __builtin_amdgcn_s_setprio(0);
        }
        if (it + 1 < 8) {   // prefetch next K fragments
            kA0 = *(const short8*)&kb[(size_t)(kt0 + 32 + krow + 0) * HD + g * 8];
            kA1 = *(const short8*)&kb[(size_t)(kt0 + 32 + krow + 4) * HD + g * 8];
        }
    }
#pragma unroll
    for (int qt4 = 0; qt4 < 4; ++qt4) {
        l_run[qt4] += __shfl_xor(l_run[qt4], 16);
        l_run[qt4] += __shfl_xor(l_run[qt4], 32);
    }
    const int rq = t >> 3, c2 = (t & 7) * 2;
    float linv = 0.f;
#pragma unroll
    for (int ch = 0; ch < 2; ++ch) {
        __syncthreads();
#pragma unroll
        for (int qt4 = 0; qt4 < 4; ++qt4)
#pragma unroll
            for (int r = 0; r < 4; ++r)
                Of[w][qt4 * 16 + 4 * g + r][ln] = oacc[qt4][ch][r];
        if (ch == 0 && g == 0)
#pragma unroll
            for (int qt4 = 0; qt4 < 4; ++qt4) Ls[w][qt4 * 16 + ln] = l_run[qt4];
        __syncthreads();
        float s0 = 0.f, s1 = 0.f;
#pragma unroll
        for (int ww = 0; ww < 8; ++ww) {
            s0 += Of[ww][rq][c2];
            s1 += Of[ww][rq][c2 + 1];
        }
        if (ch == 0) {
            float lsum = 0.f;
#pragma unroll
            for (int ww = 0; ww < 8; ++ww) lsum += Ls[ww][rq];
            linv = 1.0f / lsum;
        }
        ushort2 r2;
        r2.x = f2bf(s0 * linv);
        r2.y = f2bf(s1 * linv);
        *(ushort2*)&aout_t[((size_t)b * NN + n0 + rq) * CC + h * HD + ch * 16 + c2] = r2;
    }
}

// ---------------------------------------------------------------------------
// Stage 3: MFMA GEMM out = x + b_out + w_out @ aout (R11 verbatim).
// ---------------------------------------------------------------------------
__global__ __launch_bounds__(256) void proj_mfma(const unsigned short* __restrict__ aout_t,
                                                 const float* __restrict__ wo,
                                                 const float* __restrict__ bias,
                                                 const float* __restrict__ x,
                                                 float* __restrict__ out) {
    const int l = xcd_chunk(blockIdx.x, 512);
    const int n0 = (l & 63) * 32;
    const int bm = l >> 6;
    const int m0 = (bm & 3) * 64, b = bm >> 2;
    const int t = threadIdx.x, lane = t & 63, wid = t >> 6;
    const int g = lane >> 4, ln = lane & 15;
    __shared__ __align__(16) unsigned short Aw[4][64][36];
    __shared__ __align__(16) unsigned short Bx[4][32][36];
    f32x4 acc[2] = {};
    const unsigned short* ab = aout_t + ((size_t)b * NN + n0) * CC;
    const int sm = t & 63, sch = t >> 6;
    const int bn = t & 31, bch = t >> 5;
    for (int kh = 0; kh < 2; ++kh) {
        __syncthreads();
        {
            const float* wsrc = wo + (size_t)(m0 + sm) * CC + kh * 128 + sch * 32;
            float wv[32];
#pragma unroll
            for (int j = 0; j < 8; ++j) *(float4*)&wv[j * 4] = *(const float4*)&wsrc[j * 4];
#pragma unroll
            for (int j2 = 0; j2 < 4; ++j2) {
                ushort8 p;
#pragma unroll
                for (int e = 0; e < 8; ++e) p[e] = f2bf(wv[j2 * 8 + e]);
                *(ushort8*)&Aw[sch][sm][j2 * 8] = p;
            }
        }
        {
            int ks = bch >> 1, off = (bch & 1) * 16;
            const unsigned short* src = &ab[(size_t)bn * CC + kh * 128 + ks * 32 + off];
            *(ushort8*)&Bx[ks][bn][off]     = *(const ushort8*)&src[0];
            *(ushort8*)&Bx[ks][bn][off + 8] = *(const ushort8*)&src[8];
        }
        __syncthreads();
#pragma unroll
        for (int ks = 0; ks < 4; ++ks) {
            short8 aW = *(const short8*)&Aw[ks][wid * 16 + ln][g * 8];
#pragma unroll
            for (int nt = 0; nt < 2; ++nt) {
                short8 bX = *(const short8*)&Bx[ks][nt * 16 + ln][g * 8];
                acc[nt] = __builtin_amdgcn_mfma_f32_16x16x32_bf16(aW, bX, acc[nt], 0, 0, 0);
            }
        }
    }
    const int mbase = m0 + wid * 16 + 4 * g;
    float bv[4];
#pragma unroll
    for (int r = 0; r < 4; ++r) bv[r] = bias[mbase + r];
#pragma unroll
    for (int nt = 0; nt < 2; ++nt) {
        int n = n0 + nt * 16 + ln;
#pragma unroll
        for (int r = 0; r < 4; ++r) {
            size_t off = ((size_t)b * CC + mbase + r) * NN + n;
            out[off] = acc[nt][r] + bv[r] + x[off];
        }
    }
}

extern "C" void kernel_launch(void* const* d_in, const int* in_sizes, int n_in,
                              void* d_out, int out_size, void* d_ws, size_t ws_size,
                              hipStream_t stream) {
    const float* x     = (const float*)d_in[0];
    const float* w_qkv = (const float*)d_in[1];
    const float* b_qkv = (const float*)d_in[2];
    const float* w_out = (const float*)d_in[3];
    const float* b_out = (const float*)d_in[4];
    float* out = (float*)d_out;

    unsigned short* qt     = (unsigned short*)d_ws;                 // [2][8][2048][32]
    unsigned short* ktt    = qt  + (size_t)BB * NH * NN * HD;       // [2][8][2048][32]
    unsigned short* vt     = ktt + (size_t)BB * NH * NN * HD;       // [2][8][32][2048]
    unsigned short* aout_t = vt  + (size_t)BB * NH * NN * HD;       // [2][2048][256]

    qkv_mfma<<<dim3(768), 256, 0, stream>>>(x, w_qkv, b_qkv, qt, ktt, vt);
    attn_mfma<<<dim3(512), 512, 0, stream>>>(qt, ktt, vt, aout_t);
    proj_mfma<<<dim3(512), 256, 0, stream>>>(aout_t, w_out, b_out, x, out);
}

// Round 19
// 46.741 us; speedup vs baseline: 1.4974x; 1.4974x over previous
//
#include <hip/hip_runtime.h>
#include <hip/hip_bf16.h>
#include <math.h>

#define BB 2
#define CC 256
#define NH 8
#define HD 32
#define NN 2048
#define QBLK 64
// (1/sqrt(32)) * log2(e): softmax runs in the log2 domain
#define QK_SCALE 0.25500917f

typedef __attribute__((ext_vector_type(8))) short short8;
typedef __attribute__((ext_vector_type(8))) unsigned short ushort8;
typedef __attribute__((ext_vector_type(4))) float f32x4;

__device__ inline unsigned short f2bf(float f) {
    __hip_bfloat16 h = __float2bfloat16(f);
    return __builtin_bit_cast(unsigned short, h);
}
// bijective XCD-chunk swizzle (m204)
__device__ inline int xcd_chunk(int orig, int nwg) {
    int q = nwg >> 3, r = nwg & 7, x = orig & 7, s = orig >> 3;
    return (x < r ? x * (q + 1) : r * (q + 1) + (x - r) * q) + s;
}

// ---------------------------------------------------------------------------
// Stage 1: MFMA GEMM qkv = w_qkv @ x + b (R11 verbatim).
// ---------------------------------------------------------------------------
__global__ __launch_bounds__(256) void qkv_mfma(const float* __restrict__ x,
                                                const float* __restrict__ wq,
                                                const float* __restrict__ bias,
                                                unsigned short* __restrict__ qt,
                                                unsigned short* __restrict__ ktt,
                                                unsigned short* __restrict__ vt) {
    const int l = xcd_chunk(blockIdx.x, 768);
    const int m0 = (l % 12) * 64;
    const int xtile = l / 12;
    const int n0 = (xtile & 31) * 64;
    const int b = xtile >> 5;
    const int t = threadIdx.x, lane = t & 63, wid = t >> 6;
    const int g = lane >> 4, ln = lane & 15;
    __shared__ __align__(16) unsigned short Aw[4][64][36];
    __shared__ __align__(16) unsigned short Bx[4][64][36];
    f32x4 acc[4] = {};
    const int sm = t & 63, sch = t >> 6;
    const int pc = t >> 4, pn = t & 15;
    const int c0 = pc * 8, nl = pn * 4;
    const float* xb = x + (size_t)b * CC * NN + n0;
    for (int kh = 0; kh < 2; ++kh) {
        __syncthreads();
        {   // A: w_qkv fp32 -> bf16
            const float* wsrc = wq + (size_t)(m0 + sm) * CC + kh * 128 + sch * 32;
            float wv[32];
#pragma unroll
            for (int j = 0; j < 8; ++j) *(float4*)&wv[j * 4] = *(const float4*)&wsrc[j * 4];
#pragma unroll
            for (int j2 = 0; j2 < 4; ++j2) {
                ushort8 p;
#pragma unroll
                for (int e = 0; e < 8; ++e) p[e] = f2bf(wv[j2 * 8 + e]);
                *(ushort8*)&Aw[sch][sm][j2 * 8] = p;
            }
        }
        {   // B: x fp32 [c][n] -> bf16 [n][c] (register-patch transpose)
            const float* xsrc = xb + (size_t)(kh * 128 + c0) * NN + nl;
            float xv[8][4];
#pragma unroll
            for (int i = 0; i < 8; ++i) *(float4*)&xv[i][0] = *(const float4*)&xsrc[(size_t)i * NN];
#pragma unroll
            for (int i2 = 0; i2 < 4; ++i2) {
                ushort8 p;
#pragma unroll
                for (int e = 0; e < 8; ++e) p[e] = f2bf(xv[e][i2]);
                *(ushort8*)&Bx[pc >> 2][nl + i2][(pc & 3) * 8] = p;
            }
        }
        __syncthreads();
#pragma unroll
        for (int ks = 0; ks < 4; ++ks) {
            short8 aW = *(const short8*)&Aw[ks][wid * 16 + ln][g * 8];
#pragma unroll
            for (int nt = 0; nt < 4; ++nt) {
                short8 bX = *(const short8*)&Bx[ks][nt * 16 + ln][g * 8];
                acc[nt] = __builtin_amdgcn_mfma_f32_16x16x32_bf16(aW, bX, acc[nt], 0, 0, 0);
            }
        }
    }
    __syncthreads();
    unsigned short (*Tqk)[64][40] = (unsigned short (*)[64][40])&Aw[0][0][0];
    unsigned short (*Tv)[32][72]  = (unsigned short (*)[32][72])&Bx[0][0][0];
    {
        const int grp = wid >> 1;
        const int cl0 = (wid & 1) * 16 + 4 * g;
        const int gm0 = m0 + grp * 32;
        const int gtype = (gm0 % 96) >> 5;
        const float sc = (gtype == 0) ? QK_SCALE : 1.0f;
        float bv[4];
#pragma unroll
        for (int r = 0; r < 4; ++r) bv[r] = bias[gm0 + cl0 + r];
        if (gtype == 2) {
#pragma unroll
            for (int nt = 0; nt < 4; ++nt)
#pragma unroll
                for (int r = 0; r < 4; ++r)
                    Tv[grp][cl0 + r][nt * 16 + ln] = f2bf(acc[nt][r] + bv[r]);
        } else {
#pragma unroll
            for (int nt = 0; nt < 4; ++nt)
#pragma unroll
                for (int r = 0; r < 4; ++r)
                    Tqk[grp][nt * 16 + ln][cl0 + r] = f2bf((acc[nt][r] + bv[r]) * sc);
        }
    }
    __syncthreads();
#pragma unroll
    for (int grp2 = 0; grp2 < 2; ++grp2) {
        const int gm = m0 + grp2 * 32;
        const int gtype = (gm % 96) >> 5;
        const int head = gm / 96;
        if (gtype == 2) {
            const int cl = t >> 3, n8 = (t & 7) * 8;
            ushort8 v = *(const ushort8*)&Tv[grp2][cl][n8];
            *(ushort8*)&vt[((size_t)(b * NH + head) * HD + cl) * NN + n0 + n8] = v;
        } else {
            unsigned short* dst = (gtype == 0) ? qt : ktt;
            const int nr = t >> 2, c8 = (t & 3) * 8;
            ushort8 v = *(const ushort8*)&Tqk[grp2][nr][c8];
            *(ushort8*)&dst[((size_t)(b * NH + head) * NN + n0 + nr) * HD + c8] = v;
        }
    }
}

// ---------------------------------------------------------------------------
// Stage 2: barrier-free MFMA flash attention (R11 verbatim — proven best:
// QBLK=64, 512 blocks x 512 thr, wave w owns keys [w*256,w*256+256),
// all operands global->register, fixed-max softmax, no launch-bounds cap).
// ---------------------------------------------------------------------------
__global__ __launch_bounds__(512) void attn_mfma(const unsigned short* __restrict__ Qt,
                                                 const unsigned short* __restrict__ Kt,
                                                 const unsigned short* __restrict__ Vt,
                                                 unsigned short* __restrict__ aout_t) {
    const int l = xcd_chunk(blockIdx.x, 512);
    const int n0 = (l & 31) * QBLK;
    const int bh = l >> 5;
    const int h = bh & 7, b = bh >> 3;
    const int t = threadIdx.x;
    const int lane = t & 63, w = t >> 6;
    const int g = lane >> 4, ln = lane & 15;
    __shared__ float Of[8][64][18];
    __shared__ float Ls[8][64];
    const unsigned short* qb = Qt + ((size_t)(b * NH + h) * NN + n0) * HD;
    const unsigned short* kb = Kt + (size_t)(b * NH + h) * NN * HD;
    const unsigned short* vb = Vt + (size_t)(b * NH + h) * HD * NN;
    short8 bQ[4];
#pragma unroll
    for (int qt4 = 0; qt4 < 4; ++qt4)
        bQ[qt4] = *(const short8*)&qb[(size_t)(qt4 * 16 + ln) * HD + g * 8];
    const int krow = 8 * (ln >> 2) + (ln & 3);
    const int wkey0 = w * 256;
    f32x4 oacc[4][2];
    const f32x4 zero4 = {0.f, 0.f, 0.f, 0.f};
#pragma unroll
    for (int qt4 = 0; qt4 < 4; ++qt4) { oacc[qt4][0] = zero4; oacc[qt4][1] = zero4; }
    float l_run[4] = {0.f, 0.f, 0.f, 0.f};
    short8 kA0 = *(const short8*)&kb[(size_t)(wkey0 + krow + 0) * HD + g * 8];
    short8 kA1 = *(const short8*)&kb[(size_t)(wkey0 + krow + 4) * HD + g * 8];
    for (int it = 0; it < 8; ++it) {
        const int kt0 = wkey0 + it * 32;
        short8 bV0 = *(const short8*)&vb[(size_t)ln * NN + kt0 + g * 8];
        short8 bV1 = *(const short8*)&vb[(size_t)(16 + ln) * NN + kt0 + g * 8];
        f32x4 sacc[2][4];
        __builtin_amdgcn_s_setprio(1);
#pragma unroll
        for (int qt4 = 0; qt4 < 4; ++qt4) {
            sacc[0][qt4] = __builtin_amdgcn_mfma_f32_16x16x32_bf16(kA0, bQ[qt4], zero4, 0, 0, 0);
            sacc[1][qt4] = __builtin_amdgcn_mfma_f32_16x16x32_bf16(kA1, bQ[qt4], zero4, 0, 0, 0);
        }
        __builtin_amdgcn_s_setprio(0);
        if (it + 1 < 8) {
            kA0 = *(const short8*)&kb[(size_t)(kt0 + 32 + krow + 0) * HD + g * 8];
            kA1 = *(const short8*)&kb[(size_t)(kt0 + 32 + krow + 4) * HD + g * 8];
        }
        short8 aP[4];
#pragma unroll
        for (int qt4 = 0; qt4 < 4; ++qt4) {
#pragma unroll
            for (int u = 0; u < 2; ++u) {
#pragma unroll
                for (int r = 0; r < 4; ++r) {
                    float p = exp2f(sacc[u][qt4][r]);
                    sacc[u][qt4][r] = p;
                    aP[qt4][u * 4 + r] = (short)f2bf(p);
                }
            }
            l_run[qt4] += ((sacc[0][qt4][0] + sacc[0][qt4][1]) + (sacc[0][qt4][2] + sacc[0][qt4][3]))
                        + ((sacc[1][qt4][0] + sacc[1][qt4][1]) + (sacc[1][qt4][2] + sacc[1][qt4][3]));
        }
        __builtin_amdgcn_s_setprio(1);
#pragma unroll
        for (int qt4 = 0; qt4 < 4; ++qt4) {
            oacc[qt4][0] = __builtin_amdgcn_mfma_f32_16x16x32_bf16(aP[qt4], bV0, oacc[qt4][0], 0, 0, 0);
            oacc[qt4][1] = __builtin_amdgcn_mfma_f32_16x16x32_bf16(aP[qt4], bV1, oacc[qt4][1], 0, 0, 0);
        }
        __builtin_amdgcn_s_setprio(0);
    }
#pragma unroll
    for (int qt4 = 0; qt4 < 4; ++qt4) {
        l_run[qt4] += __shfl_xor(l_run[qt4], 16);
        l_run[qt4] += __shfl_xor(l_run[qt4], 32);
    }
    const int rq = t >> 3, c2 = (t & 7) * 2;
    float linv = 0.f;
#pragma unroll
    for (int ch = 0; ch < 2; ++ch) {
        __syncthreads();
#pragma unroll
        for (int qt4 = 0; qt4 < 4; ++qt4)
#pragma unroll
            for (int r = 0; r < 4; ++r)
                Of[w][qt4 * 16 + 4 * g + r][ln] = oacc[qt4][ch][r];
        if (ch == 0 && g == 0)
#pragma unroll
            for (int qt4 = 0; qt4 < 4; ++qt4) Ls[w][qt4 * 16 + ln] = l_run[qt4];
        __syncthreads();
        float s0 = 0.f, s1 = 0.f;
#pragma unroll
        for (int ww = 0; ww < 8; ++ww) {
            s0 += Of[ww][rq][c2];
            s1 += Of[ww][rq][c2 + 1];
        }
        if (ch == 0) {
            float lsum = 0.f;
#pragma unroll
            for (int ww = 0; ww < 8; ++ww) lsum += Ls[ww][rq];
            linv = 1.0f / lsum;
        }
        ushort2 r2;
        r2.x = f2bf(s0 * linv);
        r2.y = f2bf(s1 * linv);
        *(ushort2*)&aout_t[((size_t)b * NN + n0 + rq) * CC + h * HD + ch * 16 + c2] = r2;
    }
}

// ---------------------------------------------------------------------------
// Stage 3: MFMA GEMM out = x + b_out + w_out @ aout (R11 verbatim).
// ---------------------------------------------------------------------------
__global__ __launch_bounds__(256) void proj_mfma(const unsigned short* __restrict__ aout_t,
                                                 const float* __restrict__ wo,
                                                 const float* __restrict__ bias,
                                                 const float* __restrict__ x,
                                                 float* __restrict__ out) {
    const int l = xcd_chunk(blockIdx.x, 512);
    const int n0 = (l & 63) * 32;
    const int bm = l >> 6;
    const int m0 = (bm & 3) * 64, b = bm >> 2;
    const int t = threadIdx.x, lane = t & 63, wid = t >> 6;
    const int g = lane >> 4, ln = lane & 15;
    __shared__ __align__(16) unsigned short Aw[4][64][36];
    __shared__ __align__(16) unsigned short Bx[4][32][36];
    f32x4 acc[2] = {};
    const unsigned short* ab = aout_t + ((size_t)b * NN + n0) * CC;
    const int sm = t & 63, sch = t >> 6;
    const int bn = t & 31, bch = t >> 5;
    for (int kh = 0; kh < 2; ++kh) {
        __syncthreads();
        {
            const float* wsrc = wo + (size_t)(m0 + sm) * CC + kh * 128 + sch * 32;
            float wv[32];
#pragma unroll
            for (int j = 0; j < 8; ++j) *(float4*)&wv[j * 4] = *(const float4*)&wsrc[j * 4];
#pragma unroll
            for (int j2 = 0; j2 < 4; ++j2) {
                ushort8 p;
#pragma unroll
                for (int e = 0; e < 8; ++e) p[e] = f2bf(wv[j2 * 8 + e]);
                *(ushort8*)&Aw[sch][sm][j2 * 8] = p;
            }
        }
        {
            int ks = bch >> 1, off = (bch & 1) * 16;
            const unsigned short* src = &ab[(size_t)bn * CC + kh * 128 + ks * 32 + off];
            *(ushort8*)&Bx[ks][bn][off]     = *(const ushort8*)&src[0];
            *(ushort8*)&Bx[ks][bn][off + 8] = *(const ushort8*)&src[8];
        }
        __syncthreads();
#pragma unroll
        for (int ks = 0; ks < 4; ++ks) {
            short8 aW = *(const short8*)&Aw[ks][wid * 16 + ln][g * 8];
#pragma unroll
            for (int nt = 0; nt < 2; ++nt) {
                short8 bX = *(const short8*)&Bx[ks][nt * 16 + ln][g * 8];
                acc[nt] = __builtin_amdgcn_mfma_f32_16x16x32_bf16(aW, bX, acc[nt], 0, 0, 0);
            }
        }
    }
    const int mbase = m0 + wid * 16 + 4 * g;
    float bv[4];
#pragma unroll
    for (int r = 0; r < 4; ++r) bv[r] = bias[mbase + r];
#pragma unroll
    for (int nt = 0; nt < 2; ++nt) {
        int n = n0 + nt * 16 + ln;
#pragma unroll
        for (int r = 0; r < 4; ++r) {
            size_t off = ((size_t)b * CC + mbase + r) * NN + n;
            out[off] = acc[nt][r] + bv[r] + x[off];
        }
    }
}

extern "C" void kernel_launch(void* const* d_in, const int* in_sizes, int n_in,
                              void* d_out, int out_size, void* d_ws, size_t ws_size,
                              hipStream_t stream) {
    const float* x     = (const float*)d_in[0];
    const float* w_qkv = (const float*)d_in[1];
    const float* b_qkv = (const float*)d_in[2];
    const float* w_out = (const float*)d_in[3];
    const float* b_out = (const float*)d_in[4];
    float* out = (float*)d_out;

    unsigned short* qt     = (unsigned short*)d_ws;                 // [2][8][2048][32]
    unsigned short* ktt    = qt  + (size_t)BB * NH * NN * HD;       // [2][8][2048][32]
    unsigned short* vt     = ktt + (size_t)BB * NH * NN * HD;       // [2][8][32][2048]
    unsigned short* aout_t = vt  + (size_t)BB * NH * NN * HD;       // [2][2048][256]

    qkv_mfma<<<dim3(768), 256, 0, stream>>>(x, w_qkv, b_qkv, qt, ktt, vt);
    attn_mfma<<<dim3(512), 512, 0, stream>>>(qt, ktt, vt, aout_t);
    proj_mfma<<<dim3(512), 256, 0, stream>>>(aout_t, w_out, b_out, x, out);
}